// Round 2
// baseline (1417.611 us; speedup 1.0000x reference)
//
#include <hip/hip_runtime.h>

// Linear-chain CRF log-partition (backward DP), B=64, S=1024, T=128.
//
// One WAVE (64 threads) per chain => no s_barrier anywhere in the 1023-step
// sequential loop. Lane l owns tag rows r0=2l, r1=2l+1:
//   - E = exp(transitions) rows held entirely in VGPRs (128 x float2 = 256 regs)
//   - p exchange: ds_write_b64 + s_waitcnt lgkmcnt(0) (intra-wave only; global
//     prefetch loads stay in flight -- no vmcnt drain, unlike __syncthreads)
//   - matvec: 128 v_pk_fma_f32 per lane (4 independent acc chains)
//   - shift d = Beta~[0] broadcast via __shfl(.,0), 1-step stale; exact
//     bookkeeping: true Beta = Breg + O, O accumulates the applied shifts.

typedef float v2f __attribute__((ext_vector_type(2)));

#define B_  64
#define S_  1024
#define T_  128
#define PAD_IDX 0
#define EOS_IDX 3
#define BOT_IDX 1

__global__ __launch_bounds__(64, 1) void crf_logz_kernel(
    const int*   __restrict__ W,
    const float* __restrict__ emissions,
    const float* __restrict__ transitions,
    float*       __restrict__ out)
{
  const int b = blockIdx.x;
  const int l = threadIdx.x;            // lane 0..63
  const int r0 = 2 * l;                 // first owned tag row

  __shared__ __align__(16) float pbuf[T_];

  // ---- E rows into registers: e0[k]=exp(trans[r0, 2k:2k+2]), e1[k]=row r0+1
  v2f e0[64], e1[64];
  {
    const float2* t0 = (const float2*)(transitions + (size_t)r0 * T_);
    const float2* t1 = (const float2*)(transitions + (size_t)(r0 + 1) * T_);
    #pragma unroll
    for (int k = 0; k < 64; ++k) {
      float2 a = t0[k], c = t1[k];
      v2f ea, ec;
      ea.x = __expf(a.x); ea.y = __expf(a.y);
      ec.x = __expf(c.x); ec.y = __expf(c.y);
      e0[k] = ea; e1[k] = ec;
    }
  }

  const int*    Wrow = W + b * S_;
  const float2* emb2 = (const float2*)(emissions + (size_t)b * S_ * T_); // [S_*64]

  v2f   Breg = {0.f, 0.f};   // shifted Beta~ for rows r0, r0+1
  float d = 0.f, O = 0.f;    // current shift, accumulated offset

  // prefetch for n = S_-2 (consumes W[S_-1], em[S_-1, rows])
  int    w_cur  = Wrow[S_ - 1];
  float2 em_cur = emb2[(S_ - 1) * (T_ / 2) + l];

  for (int n = S_ - 2; n >= 0; --n) {
    int    w_nxt  = Wrow[n];
    float2 em_nxt = emb2[n * (T_ / 2) + l];

    if ((w_cur != PAD_IDX) & (w_cur != EOS_IDX)) {   // wave-uniform branch
      float p0 = __expf(em_cur.x + Breg.x - d);
      float p1 = __expf(em_cur.y + Breg.y - d);
      float2 pw; pw.x = p0; pw.y = p1;
      *(float2*)&pbuf[2 * l] = pw;                   // ds_write_b64
      asm volatile("s_waitcnt lgkmcnt(0)" ::: "memory");  // intra-wave LDS fence

      v2f a0 = {0.f, 0.f}, a1 = {0.f, 0.f}, a2 = {0.f, 0.f}, a3 = {0.f, 0.f};
      const float4* pb4 = (const float4*)pbuf;
      #pragma unroll
      for (int k = 0; k < 32; ++k) {
        float4 pv = pb4[k];                          // broadcast ds_read_b128
        v2f pl, ph;
        pl.x = pv.x; pl.y = pv.y;
        ph.x = pv.z; ph.y = pv.w;
        a0 = __builtin_elementwise_fma(e0[2 * k],     pl, a0);  // v_pk_fma_f32
        a1 = __builtin_elementwise_fma(e1[2 * k],     pl, a1);
        a2 = __builtin_elementwise_fma(e0[2 * k + 1], ph, a2);
        a3 = __builtin_elementwise_fma(e1[2 * k + 1], ph, a3);
      }
      float s0 = (a0.x + a0.y) + (a2.x + a2.y);
      float s1 = (a1.x + a1.y) + (a3.x + a3.y);
      float t0 = __logf(s0);
      float t1 = __logf(s1);
      Breg.x = t0; Breg.y = t1;
      O += d;
      d = __shfl(t0, 0);                             // Beta~[0] -> next shift
    }
    w_cur  = w_nxt;
    em_cur = em_nxt;
  }

  // ---- epilogue: f = trans[BOT,:] + em[b,0,:] + (Breg + O); logZ = lse(f)
  float2 tb = *(const float2*)(transitions + BOT_IDX * T_ + 2 * l);
  float f0 = tb.x + em_cur.x + Breg.x;
  float f1 = tb.y + em_cur.y + Breg.y;
  float m = fmaxf(f0, f1);
  #pragma unroll
  for (int off = 32; off; off >>= 1) m = fmaxf(m, __shfl_xor(m, off));
  float s = __expf(f0 - m) + __expf(f1 - m);
  #pragma unroll
  for (int off = 32; off; off >>= 1) s += __shfl_xor(s, off);
  if (l == 0) out[b] = O + m + __logf(s);
}

extern "C" void kernel_launch(void* const* d_in, const int* in_sizes, int n_in,
                              void* d_out, int out_size, void* d_ws, size_t ws_size,
                              hipStream_t stream) {
  const int*   W     = (const int*)d_in[0];
  const float* em    = (const float*)d_in[1];
  const float* trans = (const float*)d_in[2];
  float*       out   = (float*)d_out;
  (void)in_sizes; (void)n_in; (void)out_size; (void)d_ws; (void)ws_size;
  crf_logz_kernel<<<B_, 64, 0, stream>>>(W, em, trans, out);
}

// Round 3
// 731.625 us; speedup vs baseline: 1.9376x; 1.9376x over previous
//
#include <hip/hip_runtime.h>

// Linear-chain CRF log-partition (backward DP), B=64, S=1024, T=128.
//
// One block of 2 waves per chain. K-split design:
//   wave h owns E columns [64h, 64h+64); lane l owns rows 2l, 2l+1.
//   E-half = 128 f32 regs/lane (fits the 256-VGPR file; round-2's 1-wave
//   design needed 256 and spilled to scratch -> 2x regression).
// Per step:
//   p published to a WAVE-PRIVATE pbuf (intra-wave, in-order DS, no barrier)
//   partial matvec over own col half (16 broadcast ds_read_b128 + 64 pk_fma)
//   partial sums exchanged via parity-double-buffered LDS + raw
//   "s_waitcnt lgkmcnt(0); s_barrier" (NO vmcnt drain -> em prefetch,
//   2 steps deep, survives the barrier; __syncthreads would drain it).
//   Both waves then hold identical Beta rows 2l,2l+1.
// Shift d = Beta~[0] (readlane, 1-step stale); exact: true Beta = Breg + O.

typedef float v2f __attribute__((ext_vector_type(2)));

#define B_  64
#define S_  1024
#define T_  128
#define PAD_IDX 0
#define EOS_IDX 3
#define BOT_IDX 1

__global__ __launch_bounds__(128, 1) void crf_logz_kernel(
    const int*   __restrict__ W,
    const float* __restrict__ emissions,
    const float* __restrict__ transitions,
    float*       __restrict__ out)
{
  const int b   = blockIdx.x;
  const int tid = threadIdx.x;
  const int h   = tid >> 6;          // wave id = column half
  const int l   = tid & 63;          // lane
  const int r0  = 2 * l;             // first owned tag row

  __shared__ __align__(16) float pbuf[2][T_];       // per-wave private p
  __shared__ __align__(16) float part[2][2][T_];    // [wave][parity][row]

  // ---- E rows r0,r0+1, cols [64h,64h+64) in registers (64 x v2f = 128 VGPR)
  v2f Ea[32], Eb[32];
  {
    const float2* ta = (const float2*)(transitions + (size_t)r0 * T_ + 64 * h);
    const float2* tb = (const float2*)(transitions + (size_t)(r0 + 1) * T_ + 64 * h);
    #pragma unroll
    for (int k = 0; k < 32; ++k) {
      float2 x = ta[k], y = tb[k];
      v2f ea, eb;
      ea.x = __expf(x.x); ea.y = __expf(x.y);
      eb.x = __expf(y.x); eb.y = __expf(y.y);
      Ea[k] = ea; Eb[k] = eb;
    }
  }

  const int*    Wrow = W + b * S_;
  const float2* emb2 = (const float2*)(emissions + (size_t)b * S_ * T_);

  v2f   Bv = {0.f, 0.f};   // shifted Beta~ for rows r0, r0+1 (identical in both waves)
  float d = 0.f, O = 0.f;  // current shift, accumulated offset
  int   par = 0;

  // 2-deep prefetch: step n consumes W[n+1], em[n+1]
  int    w_a = Wrow[S_ - 1];
  float2 e_a = emb2[(S_ - 1) * (T_ / 2) + l];
  int    w_b = Wrow[S_ - 2];
  float2 e_b = emb2[(S_ - 2) * (T_ / 2) + l];

  for (int n = S_ - 2; n >= 0; --n) {
    int pf = n - 1; if (pf < 0) pf = 0;            // clamped: harmless re-read
    int    w_c = Wrow[pf];
    float2 e_c = emb2[pf * (T_ / 2) + l];

    if ((w_a != PAD_IDX) & (w_a != EOS_IDX)) {     // block-uniform branch
      float p0 = __expf(e_a.x + Bv.x - d);
      float p1 = __expf(e_a.y + Bv.y - d);
      float2 pw; pw.x = p0; pw.y = p1;
      *(float2*)&pbuf[h][r0] = pw;                 // intra-wave publish

      // partial matvec over own column half from OWN pbuf (in-order DS)
      v2f c0={0,0},c1={0,0},c2={0,0},c3={0,0},c4={0,0},c5={0,0},c6={0,0},c7={0,0};
      const float4* pb4 = (const float4*)(&pbuf[h][0]) + 16 * h;
      #pragma unroll
      for (int k = 0; k < 16; ++k) {
        float4 pv = pb4[k];                        // broadcast ds_read_b128
        v2f pl, ph;
        pl.x = pv.x; pl.y = pv.y;
        ph.x = pv.z; ph.y = pv.w;
        if (k & 1) {
          c4 = __builtin_elementwise_fma(Ea[2*k],   pl, c4);
          c5 = __builtin_elementwise_fma(Ea[2*k+1], ph, c5);
          c6 = __builtin_elementwise_fma(Eb[2*k],   pl, c6);
          c7 = __builtin_elementwise_fma(Eb[2*k+1], ph, c7);
        } else {
          c0 = __builtin_elementwise_fma(Ea[2*k],   pl, c0);
          c1 = __builtin_elementwise_fma(Ea[2*k+1], ph, c1);
          c2 = __builtin_elementwise_fma(Eb[2*k],   pl, c2);
          c3 = __builtin_elementwise_fma(Eb[2*k+1], ph, c3);
        }
      }
      float s0 = ((c0.x + c0.y) + (c1.x + c1.y)) + ((c4.x + c4.y) + (c5.x + c5.y));
      float s1 = ((c2.x + c2.y) + (c3.x + c3.y)) + ((c6.x + c6.y) + (c7.x + c7.y));

      float2 ps; ps.x = s0; ps.y = s1;
      *(float2*)&part[h][par][r0] = ps;            // publish partials
      // drain LDS writes, then barrier -- NO vmcnt(0): prefetch stays in flight
      asm volatile("s_waitcnt lgkmcnt(0)\n\ts_barrier" ::: "memory");
      float2 o = *(const float2*)&part[1 - h][par][r0];

      float t0 = __logf(s0 + o.x);
      float t1 = __logf(s1 + o.y);
      Bv.x = t0; Bv.y = t1;
      O += d;
      d = __shfl(t0, 0);                           // Beta~[0], identical in both waves
      par ^= 1;
    }
    w_a = w_b; e_a = e_b;
    w_b = w_c; e_b = e_c;
  }

  // ---- epilogue: f = trans[BOT,:] + em[b,0,:] + Beta~;  logZ = O + lse(f)
  if (h == 0) {
    float2 tb2 = *(const float2*)(transitions + BOT_IDX * T_ + r0);
    float f0 = tb2.x + e_a.x + Bv.x;    // e_a ended as em[b,0,r0:r0+2]
    float f1 = tb2.y + e_a.y + Bv.y;
    float m = fmaxf(f0, f1);
    #pragma unroll
    for (int off = 32; off; off >>= 1) m = fmaxf(m, __shfl_xor(m, off));
    float s = __expf(f0 - m) + __expf(f1 - m);
    #pragma unroll
    for (int off = 32; off; off >>= 1) s += __shfl_xor(s, off);
    if (l == 0) out[b] = O + m + __logf(s);
  }
}

extern "C" void kernel_launch(void* const* d_in, const int* in_sizes, int n_in,
                              void* d_out, int out_size, void* d_ws, size_t ws_size,
                              hipStream_t stream) {
  const int*   W     = (const int*)d_in[0];
  const float* em    = (const float*)d_in[1];
  const float* trans = (const float*)d_in[2];
  float*       out   = (float*)d_out;
  (void)in_sizes; (void)n_in; (void)out_size; (void)d_ws; (void)ws_size;
  crf_logz_kernel<<<B_, 128, 0, stream>>>(W, em, trans, out);
}

// Round 4
// 673.947 us; speedup vs baseline: 2.1034x; 1.0856x over previous
//
#include <hip/hip_runtime.h>

// Linear-chain CRF log-partition (backward DP), B=64, S=1024, T=128.
//
// ONE WAVE per chain, ZERO barriers. Root cause of rounds 1-3 (~1550 cyc/step
// flat): compiler rematerialized E = exp(transitions) (VGPR_Count 52/92 vs
// needed 80/168; WRITE_SIZE=2KB so no scratch) -> per-step global reloads +
// 64 exps/lane. Fix:
//   * E stored as packed f16 pairs: 2 rows x 128 cols = 128 VGPRs/lane,
//     each PINNED with asm("" : "+v") -- opaque, cannot be remat'd.
//   * matvec: 128 x v_dot2_f32_f16 per lane (fp32 accumulate).
//   * p exchange: ds_write_b32 + 16 broadcast ds_read_b128, ordered by the
//     wave's in-order DS pipe (single wave -> no barrier, no waitcnt drain).
//   * shift g = Bv[0] + 2.2 via readfirstlane (SALU, ~10cyc; not bpermute).
//     Exactness: any uniform g works -- O += g compensates. This g keeps
//     Bv in [-1.6,1.6] forever (subtracts current level exactly) and
//     p in [~4e-4, ~35]: comfortably inside f16 range.
// f16 error budget: E,p rel err ~5e-4/term -> logZ drift <= ~0.5 worst case;
// threshold is 109.4.

typedef _Float16 h2 __attribute__((ext_vector_type(2)));

#define B_  64
#define S_  1024
#define T_  128
#define PAD_IDX 0
#define EOS_IDX 3
#define BOT_IDX 1
#define TSHIFT 2.2f

#if defined(__has_builtin)
#if __has_builtin(__builtin_amdgcn_fdot2)
#define HAS_FDOT2 1
#endif
#endif

static __device__ __forceinline__ float dot2acc(unsigned eu, unsigned pu, float c) {
  h2 a = __builtin_bit_cast(h2, eu);
  h2 b = __builtin_bit_cast(h2, pu);
#ifdef HAS_FDOT2
  return __builtin_amdgcn_fdot2(a, b, c, false);
#else
  return fmaf((float)a.x, (float)b.x, fmaf((float)a.y, (float)b.y, c));
#endif
}

static __device__ __forceinline__ float bcast0(float x) {
  return __builtin_bit_cast(float,
      __builtin_amdgcn_readfirstlane(__builtin_bit_cast(int, x)));
}

__global__ __launch_bounds__(64, 1) void crf_logz_kernel(
    const int*   __restrict__ W,
    const float* __restrict__ emissions,
    const float* __restrict__ transitions,
    float*       __restrict__ out)
{
  const int b  = blockIdx.x;
  const int l  = threadIdx.x;      // lane 0..63
  const int r0 = 2 * l;            // owns tag rows r0, r0+1

  __shared__ __align__(16) unsigned pbuf[T_ / 2];   // 64 packed half2

  // ---- E rows r0, r0+1 as packed f16 pairs, pinned into VGPRs (128 regs)
  unsigned E0u[64], E1u[64];
  {
    const float2* ta = (const float2*)(transitions + (size_t)r0 * T_);
    const float2* tb = (const float2*)(transitions + (size_t)(r0 + 1) * T_);
    #pragma unroll
    for (int k = 0; k < 64; ++k) {
      float2 x = ta[k], y = tb[k];
      h2 ex, ey;
      ex.x = (_Float16)__expf(x.x); ex.y = (_Float16)__expf(x.y);
      ey.x = (_Float16)__expf(y.x); ey.y = (_Float16)__expf(y.y);
      E0u[k] = __builtin_bit_cast(unsigned, ex);
      E1u[k] = __builtin_bit_cast(unsigned, ey);
      asm volatile("" : "+v"(E0u[k]), "+v"(E1u[k]));   // pin: no remat/demote
    }
  }

  const int*    Wrow = W + b * S_;
  const float2* emb2 = (const float2*)(emissions + (size_t)b * S_ * T_);

  float2 Bv = {0.f, 0.f};   // shifted Beta for rows r0, r0+1 (true = Bv + O)
  float  O  = 0.f;
  float  g  = TSHIFT;       // current shift = (entering Bv[0]) + TSHIFT

  // 2-deep prefetch: step n consumes W[n+1], em[n+1]
  int    w_a = Wrow[S_ - 1];
  float2 e_a = emb2[(S_ - 1) * (T_ / 2) + l];
  int    w_b = Wrow[S_ - 2];
  float2 e_b = emb2[(S_ - 2) * (T_ / 2) + l];

  for (int n = S_ - 2; n >= 0; --n) {
    int pf = n - 1; if (pf < 0) pf = 0;              // clamped re-read: harmless
    int    w_c = Wrow[pf];
    float2 e_c = emb2[pf * (T_ / 2) + l];

    if ((w_a != PAD_IDX) & (w_a != EOS_IDX)) {       // wave-uniform branch
      float p0 = __expf(e_a.x + Bv.x - g);
      float p1 = __expf(e_a.y + Bv.y - g);
      h2 ph; ph.x = (_Float16)p0; ph.y = (_Float16)p1;
      pbuf[l] = __builtin_bit_cast(unsigned, ph);    // ds_write_b32
      asm volatile("" ::: "memory");                 // compile-time order only;
                                                     // HW DS pipe is in-order per wave
      float a00=0.f,a01=0.f,a02=0.f,a03=0.f;
      float a10=0.f,a11=0.f,a12=0.f,a13=0.f;
      const uint4* pb4 = (const uint4*)pbuf;
      #pragma unroll
      for (int k = 0; k < 16; ++k) {
        uint4 pv = pb4[k];                           // broadcast ds_read_b128
        a00 = dot2acc(E0u[4*k+0], pv.x, a00);
        a01 = dot2acc(E0u[4*k+1], pv.y, a01);
        a02 = dot2acc(E0u[4*k+2], pv.z, a02);
        a03 = dot2acc(E0u[4*k+3], pv.w, a03);
        a10 = dot2acc(E1u[4*k+0], pv.x, a10);
        a11 = dot2acc(E1u[4*k+1], pv.y, a11);
        a12 = dot2acc(E1u[4*k+2], pv.z, a12);
        a13 = dot2acc(E1u[4*k+3], pv.w, a13);
      }
      float s0 = (a00 + a01) + (a02 + a03);
      float s1 = (a10 + a11) + (a12 + a13);
      float s0l0 = bcast0(s0);                       // lane0's s0 (SALU, cheap)
      Bv.x = __logf(s0);
      Bv.y = __logf(s1);
      O += g;
      g = __logf(s0l0) + TSHIFT;                     // next shift = new Bv[0] + t
    }
    w_a = w_b; e_a = e_b;
    w_b = w_c; e_b = e_c;
  }

  // ---- epilogue: f = trans[BOT,:] + em[b,0,:] + Bv;  logZ = O + lse(f)
  float2 tb2 = *(const float2*)(transitions + BOT_IDX * T_ + r0);
  float f0 = tb2.x + e_a.x + Bv.x;                   // e_a ended as em[b,0,:]
  float f1 = tb2.y + e_a.y + Bv.y;
  float m = fmaxf(f0, f1);
  #pragma unroll
  for (int off = 32; off; off >>= 1) m = fmaxf(m, __shfl_xor(m, off));
  float s = __expf(f0 - m) + __expf(f1 - m);
  #pragma unroll
  for (int off = 32; off; off >>= 1) s += __shfl_xor(s, off);
  if (l == 0) out[b] = O + m + __logf(s);
}

extern "C" void kernel_launch(void* const* d_in, const int* in_sizes, int n_in,
                              void* d_out, int out_size, void* d_ws, size_t ws_size,
                              hipStream_t stream) {
  const int*   W     = (const int*)d_in[0];
  const float* em    = (const float*)d_in[1];
  const float* trans = (const float*)d_in[2];
  float*       out   = (float*)d_out;
  (void)in_sizes; (void)n_in; (void)out_size; (void)d_ws; (void)ws_size;
  crf_logz_kernel<<<B_, 64, 0, stream>>>(W, em, trans, out);
}

// Round 7
// 489.709 us; speedup vs baseline: 2.8948x; 1.3762x over previous
//
#include <hip/hip_runtime.h>

// Linear-chain CRF log-partition (backward DP), B=64, S=1024, T=128.
//
// Exp-space recurrence with DEAD-BEAT normalization (fixes r5/r6 NaNs):
//   publish   v' = q .* u .* e^{-GHAT}          (NO z feedback at publish)
//   barrier; read z = q[0] of the state being consumed (double-buffered slot)
//   update    q  <- (E * v') * rcp(z)           (uniform scale commutes)
//   Lam += GHAT + log(z)                        (exact bookkeeping)
// Level L_k = log q_k[0] obeys L_{k+1} = g_k - GHAT: bounded +-1.5, NO
// dynamics. (r6 normalized at publish with 1-step-stale z -> unit-circle
// resonator L_{k+1}=L_k-L_{k-1}+noise -> f16 overflow -> NaN.)
// Published log v' = L_k +-0.2 + em - 5.35 in [-12.2, +1.7]: inside f16
// (Beta rows flat within +-0.2 because |trans|<=0.1).
//
// Structure: 64 blocks x 4 waves; lane owns row r=(wv*32+l/2), col half
// (l&1) -> E = 32 packed-f16 VGPRs/lane (small; never demoted -- 128-reg
// variants of r2/r4 spilled). Per step: publish (1 mul + cvt + ds_write_b16);
// [lgkmcnt(0); s_barrier] (no vmcnt drain -> 4-deep em prefetch stays in
// flight); 8x broadcast ds_read_b128; 32x v_dot2_f32_f16; DPP pair-combine;
// rcp-scale. All off-path work (exp(em), log, Lam) hidden in the pipeline.

typedef _Float16 h2 __attribute__((ext_vector_type(2)));

#define B_  64
#define S_  1024
#define T_  128
#define PAD_IDX 0
#define EOS_IDX 3
#define BOT_IDX 1
#define GHAT         5.35f
#define EXP_NEG_GHAT 0.004736892f   // e^{-5.35}

#if defined(__has_builtin)
#if __has_builtin(__builtin_amdgcn_fdot2)
#define HAS_FDOT2 1
#endif
#endif

static __device__ __forceinline__ float dot2acc(unsigned eu, unsigned pu, float c) {
  h2 a = __builtin_bit_cast(h2, eu);
  h2 b = __builtin_bit_cast(h2, pu);
#ifdef HAS_FDOT2
  return __builtin_amdgcn_fdot2(a, b, c, false);
#else
  return fmaf((float)a.x, (float)b.x, fmaf((float)a.y, (float)b.y, c));
#endif
}

// add the value from the paired lane (lane ^ 1) via DPP quad_perm [1,0,3,2]
static __device__ __forceinline__ float pair_sum(float x) {
  int p = __builtin_amdgcn_update_dpp(0, __builtin_bit_cast(int, x),
                                      0xB1, 0xF, 0xF, true);
  return x + __builtin_bit_cast(float, p);
}

__global__ __launch_bounds__(256, 1) void crf_logz_kernel(
    const int*   __restrict__ W,
    const float* __restrict__ emissions,
    const float* __restrict__ transitions,
    float*       __restrict__ out)
{
  const int b    = blockIdx.x;
  const int tid  = threadIdx.x;
  const int wv   = tid >> 6;
  const int l    = tid & 63;
  const int r    = (wv << 5) + (l >> 1);   // owned tag row 0..127
  const int half = l & 1;                  // column half: 0 -> [0,64), 1 -> [64,128)

  __shared__ __align__(16) _Float16 vbuf[2][T_];  // parity double-buffered v'
  __shared__ float zslot[2];                      // parity double-buffered q[0]
  __shared__ float fbuf[T_];

  // ---- E = exp(trans[r, half*64 .. +64)) as 32 packed f16 pairs (32 VGPRs)
  unsigned Eu[32];
  {
    const float2* tr = (const float2*)(transitions + (size_t)r * T_ + (half << 6));
    #pragma unroll
    for (int k = 0; k < 32; ++k) {
      float2 x = tr[k];
      h2 e; e.x = (_Float16)__expf(x.x); e.y = (_Float16)__expf(x.y);
      Eu[k] = __builtin_bit_cast(unsigned, e);
    }
  }

  if (tid == 0) { zslot[0] = 1.0f; zslot[1] = 1.0f; }
  __syncthreads();   // once, outside the hot loop

  const int*   Wrow = W + b * S_;
  const float* emb  = emissions + (size_t)b * S_ * T_ + r;  // stride T_ per step

  float q   = 1.0f;    // exp-state for row r; true Beta_r = log q + Lam
  float Lam = 0.0f;
  int   par = 0;

  // 4-deep prefetch: at iteration n, e0/w0 hold index n+1
  int   w0 = Wrow[S_ - 1], w1 = Wrow[S_ - 2], w2 = Wrow[S_ - 3], w3 = Wrow[S_ - 4];
  float e0 = emb[(size_t)(S_ - 1) * T_];
  float e1 = emb[(size_t)(S_ - 2) * T_];
  float e2 = emb[(size_t)(S_ - 3) * T_];
  float e3 = emb[(size_t)(S_ - 4) * T_];
  float us0 = __expf(e0) * EXP_NEG_GHAT;   // u * e^{-GHAT}, ready for publish
  float us1 = __expf(e1) * EXP_NEG_GHAT;

  for (int n = S_ - 2; n >= 0; --n) {
    // keep E alive in VGPRs (remat/demotion guard) -- zero instructions
    asm volatile("" :: "v"(Eu[0]),  "v"(Eu[1]),  "v"(Eu[2]),  "v"(Eu[3]),
                       "v"(Eu[4]),  "v"(Eu[5]),  "v"(Eu[6]),  "v"(Eu[7]),
                       "v"(Eu[8]),  "v"(Eu[9]),  "v"(Eu[10]), "v"(Eu[11]),
                       "v"(Eu[12]), "v"(Eu[13]), "v"(Eu[14]), "v"(Eu[15]));
    asm volatile("" :: "v"(Eu[16]), "v"(Eu[17]), "v"(Eu[18]), "v"(Eu[19]),
                       "v"(Eu[20]), "v"(Eu[21]), "v"(Eu[22]), "v"(Eu[23]),
                       "v"(Eu[24]), "v"(Eu[25]), "v"(Eu[26]), "v"(Eu[27]),
                       "v"(Eu[28]), "v"(Eu[29]), "v"(Eu[30]), "v"(Eu[31]));

    int pf = n - 3; if (pf < 0) pf = 0;            // clamped tail re-read: harmless
    int   wn = Wrow[pf];
    float en = emb[(size_t)pf * T_];

    if ((w0 != PAD_IDX) & (w0 != EOS_IDX)) {       // block-uniform branch
      // publish v' = q * u * e^{-GHAT}  (us0 precomputed off-path)
      float v = q * us0;
      vbuf[par][r] = (_Float16)v;                  // pair-lanes write same data
      // drain own DS writes, then barrier; NO vmcnt drain (prefetch in flight)
      asm volatile("s_waitcnt lgkmcnt(0)\n\ts_barrier" ::: "memory");

      float z = zslot[par];                        // q[0] of the state consumed NOW
      const uint4* vb = ((const uint4*)(&vbuf[par][0])) + (half << 3);
      float a0 = 0.f, a1 = 0.f, a2 = 0.f, a3 = 0.f;
      #pragma unroll
      for (int k = 0; k < 8; ++k) {
        uint4 pv = vb[k];                          // 2-way broadcast ds_read_b128
        a0 = dot2acc(Eu[4*k+0], pv.x, a0);
        a1 = dot2acc(Eu[4*k+1], pv.y, a1);
        a2 = dot2acc(Eu[4*k+2], pv.z, a2);
        a3 = dot2acc(Eu[4*k+3], pv.w, a3);
      }
      float s_half = (a0 + a1) + (a2 + a3);
      float s = pair_sum(s_half);                  // full row sum, both pair-lanes

      float rz = __builtin_amdgcn_rcpf(z);         // uniform across lanes
      q = s * rz;                                  // dead-beat: L_{k+1} = g_k - GHAT
      if (tid == 0) zslot[par ^ 1] = q;            // row 0's value for NEXT step
      Lam += GHAT + __logf(z);                     // exact compensation (off-path)
      par ^= 1;
    }
    // shift prefetch pipeline
    w0 = w1; e0 = e1; us0 = us1;
    w1 = w2; e1 = e2;
    w2 = w3; e2 = e3;
    w3 = wn; e3 = en;
    us1 = __expf(e1) * EXP_NEG_GHAT;               // e1 = index n, used at iter n-1
  }

  // ---- epilogue: f_r = trans[BOT,r] + em[b,0,r] + log q_r + Lam
  float f = transitions[BOT_IDX * T_ + r] + e0 + __logf(q);
  fbuf[r] = f;                                     // pair-lanes duplicate: benign
  __syncthreads();
  if (tid < 64) {
    float x0 = fbuf[tid], x1 = fbuf[tid + 64];
    float m = fmaxf(x0, x1);
    #pragma unroll
    for (int off = 32; off; off >>= 1) m = fmaxf(m, __shfl_xor(m, off));
    float s = __expf(x0 - m) + __expf(x1 - m);
    #pragma unroll
    for (int off = 32; off; off >>= 1) s += __shfl_xor(s, off);
    if (tid == 0) out[b] = Lam + m + __logf(s);
  }
}

extern "C" void kernel_launch(void* const* d_in, const int* in_sizes, int n_in,
                              void* d_out, int out_size, void* d_ws, size_t ws_size,
                              hipStream_t stream) {
  const int*   W     = (const int*)d_in[0];
  const float* em    = (const float*)d_in[1];
  const float* trans = (const float*)d_in[2];
  float*       out   = (float*)d_out;
  (void)in_sizes; (void)n_in; (void)out_size; (void)d_ws; (void)ws_size;
  crf_logz_kernel<<<B_, 256, 0, stream>>>(W, em, trans, out);
}